// Round 13
// baseline (71.677 us; speedup 1.0000x reference)
//
#include <hip/hip_runtime.h>

// Causal flash-attention forward. B=4, L=2048, H=8, E=64, fp32 in/out.
// Layout: [B, L, H, E] -> ((b*L + l)*H + h)*E + e ; row stride H*E = 512 floats.
//
// prepass: K and V^T -> f16 tiles in d_ws in FRAGMENT-CONSUMPTION order
//   (frag j of a 64x64 tile at tile_base + j*1024 + lane*16).
// main: 256-thread blocks (4 waves, NO barriers, no LDS), 64-row q-tile per
//   block, all 4 waves walking the SAME kv tiles (identical addrs -> L1 hit).
//   SPLIT-K: q-tiles 16..31 are split into two kv-halves -> 1536 near-uniform
//   blocks (~6/CU resident at VGPR~64 -> ~24 waves/CU vs R8's 8.3; R12 showed
//   resident waves, not VMEM bytes, governs time). Split blocks emit
//   unnormalized O + per-row l,m partials; merge kernel combines with exact
//   max-rescale. Full-tile register lookahead; static-max softmax (m=8,
//   __any guard + slow path); plain stores (R7-R10 nt-stores inflated WRITE).

#define Bc 4
#define Lc 2048
#define Hc 8
#define Ec 64
#define TILEB 8192
#define NKV 32
#define BHB ((size_t)NKV * TILEB)      // 256 KB per bh
#define WSV ((size_t)32 * BHB)         // V images at +8 MB
#define WSP ((size_t)64 * BHB)         // partials at +16 MB
#define SLOT 17408                     // 16 KB O + 256 B lsum + 256 B m + pad

using f32x4 = __attribute__((ext_vector_type(4))) float;
using f16x8 = __attribute__((ext_vector_type(8))) _Float16;
using f16x4 = __attribute__((ext_vector_type(4))) _Float16;
using hf16x2 = __fp16 __attribute__((ext_vector_type(2)));
using u32x4 = __attribute__((ext_vector_type(4))) unsigned int;

static __device__ __forceinline__ unsigned int pk2(float lo, float hi) {
    union { hf16x2 h; unsigned int u; } c;
    c.h = __builtin_amdgcn_cvt_pkrtz(lo, hi);
    return c.u;
}
static __device__ __forceinline__ u32x4 nt16(const void* p) {
    return __builtin_nontemporal_load((const u32x4*)p);
}

// ---------------- prepass: fp32 -> f16 fragment-ordered tile images ----------
__global__ __launch_bounds__(256)
void prep_kernel(const float* __restrict__ K, const float* __restrict__ V,
                 char* __restrict__ ws)
{
    __shared__ char kst[64 * 128];
    __shared__ char vst[64 * 144];
    __shared__ char vtt[64 * 128];

    const int bid = blockIdx.x;
    const int bh = bid >> 5, kt = bid & 31;
    const int b = bh >> 3, h = bh & 7;
    const int tid = threadIdx.x;
    const size_t base = (size_t)b * Lc * Hc * Ec + (size_t)h * Ec;

    {   // phase A: load (nontemporal - read once) + convert rows
        const int r = tid >> 2, q4 = tid & 3, c0 = 16 * q4;
        const float* kp = K + base + (size_t)(kt * 64 + r) * 512 + c0;
        const float* vp = V + base + (size_t)(kt * 64 + r) * 512 + c0;
        unsigned int wk[8], wv[8];
        #pragma unroll
        for (int i = 0; i < 4; ++i) {
            union { u32x4 v; float f[4]; } fk, fv;
            fk.v = nt16(kp + 4 * i);
            fv.v = nt16(vp + 4 * i);
            wk[2*i]   = pk2(fk.f[0], fk.f[1]); wk[2*i+1] = pk2(fk.f[2], fk.f[3]);
            wv[2*i]   = pk2(fv.f[0], fv.f[1]); wv[2*i+1] = pk2(fv.f[2], fv.f[3]);
        }
        *(uint4*)(kst + r * 128 + 2 * c0)      = *(uint4*)&wk[0];
        *(uint4*)(kst + r * 128 + 2 * c0 + 16) = *(uint4*)&wk[4];
        *(uint4*)(vst + r * 144 + 2 * c0)      = *(uint4*)&wv[0];
        *(uint4*)(vst + r * 144 + 2 * c0 + 16) = *(uint4*)&wv[4];
    }
    __syncthreads();
    {   // phase B: transpose V -> V^T
        const int e = tid >> 2, kq = tid & 3, kv0 = 16 * kq;
        unsigned int w[8];
        #pragma unroll
        for (int i = 0; i < 8; ++i) {
            unsigned int lo = *(const unsigned short*)(vst + (kv0 + 2*i)     * 144 + 2*e);
            unsigned int hi = *(const unsigned short*)(vst + (kv0 + 2*i + 1) * 144 + 2*e);
            w[i] = lo | (hi << 16);
        }
        *(uint4*)(vtt + e * 128 + 2 * kv0)      = *(uint4*)&w[0];
        *(uint4*)(vtt + e * 128 + 2 * kv0 + 16) = *(uint4*)&w[4];
    }
    __syncthreads();
    {   // phase C: emit fragment-ordered images
        const int lane = tid & 63, qq = tid >> 6;
        const int l15 = lane & 15, l4 = lane >> 4;
        char* ko = ws + (size_t)bh * BHB + (size_t)kt * TILEB;
        char* vo = ws + WSV + (size_t)bh * BHB + (size_t)kt * TILEB;
        uint4 k0 = *(const uint4*)(kst + (16 * qq + l15) * 128 + 16 * l4);
        uint4 k1 = *(const uint4*)(kst + (16 * qq + l15) * 128 + 64 + 16 * l4);
        *(uint4*)(ko + (2 * qq)     * 1024 + lane * 16) = k0;
        *(uint4*)(ko + (2 * qq + 1) * 1024 + lane * 16) = k1;
        unsigned long long vv[4];
        #pragma unroll
        for (int c = 0; c < 4; ++c)
            vv[c] = *(const unsigned long long*)(vtt + (16 * c + l15) * 128 + 32 * qq + 8 * l4);
        uint4 v01, v23;
        v01.x = (unsigned)vv[0]; v01.y = (unsigned)(vv[0] >> 32);
        v01.z = (unsigned)vv[1]; v01.w = (unsigned)(vv[1] >> 32);
        v23.x = (unsigned)vv[2]; v23.y = (unsigned)(vv[2] >> 32);
        v23.z = (unsigned)vv[3]; v23.w = (unsigned)(vv[3] >> 32);
        *(uint4*)(vo + (2 * qq)     * 1024 + lane * 16) = v01;
        *(uint4*)(vo + (2 * qq + 1) * 1024 + lane * 16) = v23;
    }
}

// ---- main: 4 waves/block, no barriers, chunk-fused stream, split-K option ---
template<bool SPLIT>
__global__ __launch_bounds__(256, 4)
void fa_fwd_kernel(const float* __restrict__ Q, char* __restrict__ ws,
                   float* __restrict__ Out)
{
    const int bid = blockIdx.x;
    int qt, bh, kt0, kt1;
    bool wpart = false;
    char* slotp = nullptr;
    if (SPLIT) {
        if (bid < 1024) {               // split halves of q-tiles 31..16
            const int sq = bid >> 6; qt = 31 - sq;
            const int rem = bid & 63;
            const int half = rem >> 5; bh = rem & 31;
            const int n0 = (qt + 2) >> 1;          // ceil((qt+1)/2)
            kt0 = half ? n0 : 0;
            kt1 = half ? (qt + 1) : n0;
            wpart = true;
            slotp = ws + WSP + (size_t)((sq << 6) + (bh << 1) + half) * SLOT;
        } else {                        // unsplit q-tiles 15..0
            const int u = bid - 1024;
            qt = 15 - (u >> 5); bh = u & 31;
            kt0 = 0; kt1 = qt + 1;
        }
    } else {
        qt = 31 - (bid >> 5); bh = bid & 31;
        kt0 = 0; kt1 = qt + 1;
    }
    const int b = bh >> 3, h = bh & 7;

    const int tid  = threadIdx.x;
    const int wid  = tid >> 6;                // 0..3
    const int lane = tid & 63;
    const int l15  = lane & 15, l4 = lane >> 4;

    const size_t base = (size_t)b * Lc * Hc * Ec + (size_t)h * Ec;
    const char* kimg = ws + (size_t)bh * BHB + lane * 16;
    const char* vimg = ws + WSV + (size_t)bh * BHB + lane * 16;
    const float SL2E = 0.125f * 1.44269504088896340736f;

    const int qrow0 = qt * 64 + 16 * wid;
    const int q_g = qrow0 + l15;

    // Q fragment (B-operand, 16 rows), nontemporal, prescaled by scale*log2e
    f16x8 qa0, qa1;
    {
        const float* qpr = Q + base + (size_t)q_g * 512 + 8 * l4;
        union { u32x4 v; float f[4]; } f0, f1, f2, f3;
        f0.v = nt16(qpr);      f1.v = nt16(qpr + 4);
        f2.v = nt16(qpr + 32); f3.v = nt16(qpr + 36);
        union { f16x8 v; unsigned int u[4]; } pk;
        pk.u[0] = pk2(f0.f[0] * SL2E, f0.f[1] * SL2E);
        pk.u[1] = pk2(f0.f[2] * SL2E, f0.f[3] * SL2E);
        pk.u[2] = pk2(f1.f[0] * SL2E, f1.f[1] * SL2E);
        pk.u[3] = pk2(f1.f[2] * SL2E, f1.f[3] * SL2E);
        qa0 = pk.v;
        pk.u[0] = pk2(f2.f[0] * SL2E, f2.f[1] * SL2E);
        pk.u[1] = pk2(f2.f[2] * SL2E, f2.f[3] * SL2E);
        pk.u[2] = pk2(f3.f[0] * SL2E, f3.f[1] * SL2E);
        pk.u[3] = pk2(f3.f[2] * SL2E, f3.f[3] * SL2E);
        qa1 = pk.v;
    }

    f32x4 o[4] = {};
    float lsum = 0.f;                 // per-lane partial row-sum of P
    float m_run = 8.0f;               // static max bound (exp2 units)

    uint4 kf[8], vf[8];
    #pragma unroll
    for (int j = 0; j < 8; ++j) kf[j] = *(const uint4*)(kimg + (size_t)kt0 * TILEB + j * 1024);
    #pragma unroll
    for (int j = 0; j < 8; ++j) vf[j] = *(const uint4*)(vimg + (size_t)kt0 * TILEB + j * 1024);

    #pragma unroll 1
    for (int kt = kt0; kt < kt1; ++kt) {
        const bool last = (kt == qt);             // diagonal tile (mask)
        const int nxt = (kt + 1 < kt1) ? kt + 1 : kt0;   // clamp: harmless reload
        const char* kp = kimg + (size_t)nxt * TILEB;
        const char* vp = vimg + (size_t)nxt * TILEB;

        #pragma unroll
        for (int m = 0; m < 4; ++m) {
            // ---- QK chunk m: S[kv=64kt+16m+4*l4+r][q] (exp2 units)
            union { uint4 u; f16x8 h; } a0, a1;
            a0.u = kf[2 * m]; a1.u = kf[2 * m + 1];
            f32x4 s = {0.f, 0.f, 0.f, 0.f};
            s = __builtin_amdgcn_mfma_f32_16x16x32_f16(a0.h, qa0, s, 0, 0, 0);
            s = __builtin_amdgcn_mfma_f32_16x16x32_f16(a1.h, qa1, s, 0, 0, 0);

            kf[2 * m]     = *(const uint4*)(kp + (2 * m)     * 1024);
            kf[2 * m + 1] = *(const uint4*)(kp + (2 * m + 1) * 1024);

            if (last) {
                #pragma unroll
                for (int r2 = 0; r2 < 4; ++r2) {
                    const int kv_g = kt * 64 + 16 * m + 4 * l4 + r2;
                    if (kv_g > q_g) s[r2] = -1e30f;
                }
            }

            const float cmax = fmaxf(fmaxf(s[0], s[1]), fmaxf(s[2], s[3]));
            if (__any(cmax > m_run)) {            // slow path: never for N(0,1)
                float pm = cmax;
                pm = fmaxf(pm, __shfl_xor(pm, 16, 64));
                pm = fmaxf(pm, __shfl_xor(pm, 32, 64));
                const float m_new = fmaxf(m_run, pm);
                const float fac = __builtin_exp2f(m_run - m_new);
                m_run = m_new;
                lsum *= fac;
                float fr[4];
                #pragma unroll
                for (int r2 = 0; r2 < 4; ++r2) fr[r2] = __shfl(fac, 4 * l4 + r2, 64);
                #pragma unroll
                for (int c = 0; c < 4; ++c)
                    #pragma unroll
                    for (int r2 = 0; r2 < 4; ++r2) o[c][r2] *= fr[r2];
            }

            const float p0 = __builtin_exp2f(s[0] - m_run);
            const float p1 = __builtin_exp2f(s[1] - m_run);
            const float p2 = __builtin_exp2f(s[2] - m_run);
            const float p3 = __builtin_exp2f(s[3] - m_run);
            lsum += (p0 + p1) + (p2 + p3);
            union { f16x4 h; unsigned int u[2]; } pa;
            pa.u[0] = pk2(p0, p1);
            pa.u[1] = pk2(p2, p3);

            union { uint4 u; f16x4 h[2]; } w0, w1;
            w0.u = vf[2 * m]; w1.u = vf[2 * m + 1];
            o[0] = __builtin_amdgcn_mfma_f32_16x16x16f16(pa.h, w0.h[0], o[0], 0, 0, 0);
            o[1] = __builtin_amdgcn_mfma_f32_16x16x16f16(pa.h, w0.h[1], o[1], 0, 0, 0);
            o[2] = __builtin_amdgcn_mfma_f32_16x16x16f16(pa.h, w1.h[0], o[2], 0, 0, 0);
            o[3] = __builtin_amdgcn_mfma_f32_16x16x16f16(pa.h, w1.h[1], o[3], 0, 0, 0);

            vf[2 * m]     = *(const uint4*)(vp + (2 * m)     * 1024);
            vf[2 * m + 1] = *(const uint4*)(vp + (2 * m + 1) * 1024);
        }
    }

    // finish l: sum the 4 l4-group partials -> per-row total (q = l15 domain)
    lsum += __shfl_xor(lsum, 16, 64);
    lsum += __shfl_xor(lsum, 32, 64);

    if (SPLIT && wpart) {
        // emit partial: unnormalized O tile [64][64] f32 + per-row l, m
        float* po = (float*)slotp;
        #pragma unroll
        for (int c = 0; c < 4; ++c)
            #pragma unroll
            for (int r2 = 0; r2 < 4; ++r2)
                po[(16 * wid + 4 * l4 + r2) * 64 + 16 * c + l15] = o[c][r2];
        if (l4 == 0) {
            ((float*)(slotp + 16384))[16 * wid + l15] = lsum;
            ((float*)(slotp + 16640))[16 * wid + l15] = m_run;
        }
    } else {
        const float inv = 1.0f / lsum;            // q = l15 domain
        float ir[4];
        #pragma unroll
        for (int r2 = 0; r2 < 4; ++r2) ir[r2] = __shfl(inv, 4 * l4 + r2, 64);
        float* op = Out + base;
        #pragma unroll
        for (int c = 0; c < 4; ++c)
            #pragma unroll
            for (int r2 = 0; r2 < 4; ++r2)
                op[(size_t)(qrow0 + 4 * l4 + r2) * 512 + 16 * c + l15] = o[c][r2] * ir[r2];
    }
}

// ---- merge: combine the two kv-halves of each split q-tile (exact rescale) --
__global__ __launch_bounds__(256)
void merge_kernel(const char* __restrict__ ws, float* __restrict__ Out)
{
    const int bid = blockIdx.x;               // 512 = 16 qt x 32 bh
    const int sq = bid >> 5;                  // 0..15 -> qt = 31-sq
    const int qt = 31 - sq;
    const int bh = bid & 31;
    const int b = bh >> 3, h = bh & 7;
    const char* s0 = ws + WSP + (size_t)((sq << 6) + (bh << 1)) * SLOT;
    const char* s1 = s0 + SLOT;

    const int tid = threadIdx.x;
    const int row = tid >> 2, cq = tid & 3;   // row 0..63, col group 0..3

    const float l0 = ((const float*)(s0 + 16384))[row];
    const float l1 = ((const float*)(s1 + 16384))[row];
    const float m0 = ((const float*)(s0 + 16640))[row];
    const float m1 = ((const float*)(s1 + 16640))[row];
    const float ms = fmaxf(m0, m1);
    const float w0 = __builtin_exp2f(m0 - ms);
    const float w1 = __builtin_exp2f(m1 - ms);
    const float inv = 1.0f / (l0 * w0 + l1 * w1);

    const float* o0 = (const float*)s0 + row * 64 + 16 * cq;
    const float* o1 = (const float*)s1 + row * 64 + 16 * cq;
    float* op = Out + (size_t)b * Lc * Hc * Ec + (size_t)h * Ec
              + (size_t)(qt * 64 + row) * 512 + 16 * cq;
    #pragma unroll
    for (int i = 0; i < 4; ++i) {
        float4 a = *(const float4*)(o0 + 4 * i);
        float4 c = *(const float4*)(o1 + 4 * i);
        float4 r;
        r.x = (a.x * w0 + c.x * w1) * inv;
        r.y = (a.y * w0 + c.y * w1) * inv;
        r.z = (a.z * w0 + c.z * w1) * inv;
        r.w = (a.w * w0 + c.w * w1) * inv;
        *(float4*)(op + 4 * i) = r;
    }
}

extern "C" void kernel_launch(void* const* d_in, const int* in_sizes, int n_in,
                              void* d_out, int out_size, void* d_ws, size_t ws_size,
                              hipStream_t stream) {
    const float* Q = (const float*)d_in[0];
    const float* K = (const float*)d_in[1];
    const float* V = (const float*)d_in[2];
    float* O = (float*)d_out;
    char* ws = (char*)d_ws;
    const size_t NEED = WSP + (size_t)1024 * SLOT;   // ~33.8 MB
    prep_kernel<<<dim3(32 * NKV), dim3(256), 0, stream>>>(K, V, ws);
    if (ws_size >= NEED) {
        fa_fwd_kernel<true><<<dim3(1536), dim3(256), 0, stream>>>(Q, ws, O);
        merge_kernel<<<dim3(512), dim3(256), 0, stream>>>(ws, O);
    } else {
        fa_fwd_kernel<false><<<dim3(1024), dim3(256), 0, stream>>>(Q, ws, O);
    }
}

// Round 14
// 65.727 us; speedup vs baseline: 1.0905x; 1.0905x over previous
//
#include <hip/hip_runtime.h>

// Causal flash-attention forward. B=4, L=2048, H=8, E=64, fp32 in/out.
// Layout: [B, L, H, E] -> ((b*L + l)*H + h)*E + e ; row stride H*E = 512 floats.
//
// prepass: K and V^T -> f16 tiles in d_ws in FRAGMENT-CONSUMPTION order
//   (frag j of a 64x64 tile at tile_base + j*1024 + lane*16).
// main: 4096 SINGLE-WAVE blocks (64 thr), one 16-row q-tile each, NO barriers,
//   no LDS. Finest-grain residency (~16 waves/CU, instant backfill; R8-R13's
//   256-thr blocks quantized residency to 3-4 blocks/CU and convoyed).
//   Per-16-row causal extent saves ~11% tile work. bid%8 XCD round-robin x
//   bh=bid&31 -> each XCD touches only 4 bh = 2 MB K/V images (L2-resident).
//   Chunk-fused static-max softmax stream (m=8 exp2-units, __any guard + slow
//   path), full-tile register lookahead, plain stores.

#define Bc 4
#define Lc 2048
#define Hc 8
#define Ec 64
#define TILEB 8192
#define NKV 32
#define BHB ((size_t)NKV * TILEB)      // 256 KB per bh
#define WSV ((size_t)32 * BHB)         // V images at +8 MB

using f32x4 = __attribute__((ext_vector_type(4))) float;
using f16x8 = __attribute__((ext_vector_type(8))) _Float16;
using f16x4 = __attribute__((ext_vector_type(4))) _Float16;
using hf16x2 = __fp16 __attribute__((ext_vector_type(2)));
using u32x4 = __attribute__((ext_vector_type(4))) unsigned int;

static __device__ __forceinline__ unsigned int pk2(float lo, float hi) {
    union { hf16x2 h; unsigned int u; } c;
    c.h = __builtin_amdgcn_cvt_pkrtz(lo, hi);
    return c.u;
}
static __device__ __forceinline__ u32x4 nt16(const void* p) {
    return __builtin_nontemporal_load((const u32x4*)p);
}

// ---------------- prepass: fp32 -> f16 fragment-ordered tile images ----------
__global__ __launch_bounds__(256)
void prep_kernel(const float* __restrict__ K, const float* __restrict__ V,
                 char* __restrict__ ws)
{
    __shared__ char kst[64 * 128];
    __shared__ char vst[64 * 144];
    __shared__ char vtt[64 * 128];

    const int bid = blockIdx.x;
    const int bh = bid >> 5, kt = bid & 31;
    const int b = bh >> 3, h = bh & 7;
    const int tid = threadIdx.x;
    const size_t base = (size_t)b * Lc * Hc * Ec + (size_t)h * Ec;

    {   // phase A: load (nontemporal - read once) + convert rows
        const int r = tid >> 2, q4 = tid & 3, c0 = 16 * q4;
        const float* kp = K + base + (size_t)(kt * 64 + r) * 512 + c0;
        const float* vp = V + base + (size_t)(kt * 64 + r) * 512 + c0;
        unsigned int wk[8], wv[8];
        #pragma unroll
        for (int i = 0; i < 4; ++i) {
            union { u32x4 v; float f[4]; } fk, fv;
            fk.v = nt16(kp + 4 * i);
            fv.v = nt16(vp + 4 * i);
            wk[2*i]   = pk2(fk.f[0], fk.f[1]); wk[2*i+1] = pk2(fk.f[2], fk.f[3]);
            wv[2*i]   = pk2(fv.f[0], fv.f[1]); wv[2*i+1] = pk2(fv.f[2], fv.f[3]);
        }
        *(uint4*)(kst + r * 128 + 2 * c0)      = *(uint4*)&wk[0];
        *(uint4*)(kst + r * 128 + 2 * c0 + 16) = *(uint4*)&wk[4];
        *(uint4*)(vst + r * 144 + 2 * c0)      = *(uint4*)&wv[0];
        *(uint4*)(vst + r * 144 + 2 * c0 + 16) = *(uint4*)&wv[4];
    }
    __syncthreads();
    {   // phase B: transpose V -> V^T
        const int e = tid >> 2, kq = tid & 3, kv0 = 16 * kq;
        unsigned int w[8];
        #pragma unroll
        for (int i = 0; i < 8; ++i) {
            unsigned int lo = *(const unsigned short*)(vst + (kv0 + 2*i)     * 144 + 2*e);
            unsigned int hi = *(const unsigned short*)(vst + (kv0 + 2*i + 1) * 144 + 2*e);
            w[i] = lo | (hi << 16);
        }
        *(uint4*)(vtt + e * 128 + 2 * kv0)      = *(uint4*)&w[0];
        *(uint4*)(vtt + e * 128 + 2 * kv0 + 16) = *(uint4*)&w[4];
    }
    __syncthreads();
    {   // phase C: emit fragment-ordered images
        const int lane = tid & 63, qq = tid >> 6;
        const int l15 = lane & 15, l4 = lane >> 4;
        char* ko = ws + (size_t)bh * BHB + (size_t)kt * TILEB;
        char* vo = ws + WSV + (size_t)bh * BHB + (size_t)kt * TILEB;
        uint4 k0 = *(const uint4*)(kst + (16 * qq + l15) * 128 + 16 * l4);
        uint4 k1 = *(const uint4*)(kst + (16 * qq + l15) * 128 + 64 + 16 * l4);
        *(uint4*)(ko + (2 * qq)     * 1024 + lane * 16) = k0;
        *(uint4*)(ko + (2 * qq + 1) * 1024 + lane * 16) = k1;
        unsigned long long vv[4];
        #pragma unroll
        for (int c = 0; c < 4; ++c)
            vv[c] = *(const unsigned long long*)(vtt + (16 * c + l15) * 128 + 32 * qq + 8 * l4);
        uint4 v01, v23;
        v01.x = (unsigned)vv[0]; v01.y = (unsigned)(vv[0] >> 32);
        v01.z = (unsigned)vv[1]; v01.w = (unsigned)(vv[1] >> 32);
        v23.x = (unsigned)vv[2]; v23.y = (unsigned)(vv[2] >> 32);
        v23.z = (unsigned)vv[3]; v23.w = (unsigned)(vv[3] >> 32);
        *(uint4*)(vo + (2 * qq)     * 1024 + lane * 16) = v01;
        *(uint4*)(vo + (2 * qq + 1) * 1024 + lane * 16) = v23;
    }
}

// ---- main: single-wave blocks, 16 q-rows each, no barriers, no LDS ---------
__global__ __launch_bounds__(64, 4)
void fa_fwd_kernel(const float* __restrict__ Q, const char* __restrict__ ws,
                   float* __restrict__ Out)
{
    const int bid = blockIdx.x;               // 4096 = 128 q16 x 32 bh
    const int q16 = 127 - (bid >> 5);         // longest q-extents first
    const int bh  = bid & 31;                 // bid%8 -> XCD; bh%8 fixed per XCD
    const int b   = bh >> 3, h = bh & 7;

    const int lane = threadIdx.x;             // 0..63
    const int l15  = lane & 15, l4 = lane >> 4;

    const size_t base = (size_t)b * Lc * Hc * Ec + (size_t)h * Ec;
    const char* kimg = ws + (size_t)bh * BHB + lane * 16;
    const char* vimg = ws + WSV + (size_t)bh * BHB + lane * 16;
    const float SL2E = 0.125f * 1.44269504088896340736f;

    const int qrow0 = q16 * 16;
    const int mysteps = (q16 >> 2) + 1;       // per-16-row causal extent
    const int q_g = qrow0 + l15;

    // Q fragment (B-operand, 16 rows), nontemporal, prescaled by scale*log2e
    f16x8 qa0, qa1;
    {
        const float* qpr = Q + base + (size_t)q_g * 512 + 8 * l4;
        union { u32x4 v; float f[4]; } f0, f1, f2, f3;
        f0.v = nt16(qpr);      f1.v = nt16(qpr + 4);
        f2.v = nt16(qpr + 32); f3.v = nt16(qpr + 36);
        union { f16x8 v; unsigned int u[4]; } pk;
        pk.u[0] = pk2(f0.f[0] * SL2E, f0.f[1] * SL2E);
        pk.u[1] = pk2(f0.f[2] * SL2E, f0.f[3] * SL2E);
        pk.u[2] = pk2(f1.f[0] * SL2E, f1.f[1] * SL2E);
        pk.u[3] = pk2(f1.f[2] * SL2E, f1.f[3] * SL2E);
        qa0 = pk.v;
        pk.u[0] = pk2(f2.f[0] * SL2E, f2.f[1] * SL2E);
        pk.u[1] = pk2(f2.f[2] * SL2E, f2.f[3] * SL2E);
        pk.u[2] = pk2(f3.f[0] * SL2E, f3.f[1] * SL2E);
        pk.u[3] = pk2(f3.f[2] * SL2E, f3.f[3] * SL2E);
        qa1 = pk.v;
    }

    f32x4 o[4] = {};
    float lsum = 0.f;                 // per-lane partial row-sum of P
    float m_run = 8.0f;               // static max bound (exp2 units)

    uint4 kf[8], vf[8];
    #pragma unroll
    for (int j = 0; j < 8; ++j) kf[j] = *(const uint4*)(kimg + j * 1024);
    #pragma unroll
    for (int j = 0; j < 8; ++j) vf[j] = *(const uint4*)(vimg + j * 1024);

    #pragma unroll 1
    for (int kt = 0; kt < mysteps; ++kt) {
        const bool last = (kt == mysteps - 1);    // diagonal tile (mask)
        const int nxt = last ? 0 : kt + 1;        // clamp: harmless reload
        const char* kp = kimg + (size_t)nxt * TILEB;
        const char* vp = vimg + (size_t)nxt * TILEB;

        #pragma unroll
        for (int m = 0; m < 4; ++m) {
            // ---- QK chunk m: S[kv=64kt+16m+4*l4+r][q] (exp2 units)
            union { uint4 u; f16x8 h; } a0, a1;
            a0.u = kf[2 * m]; a1.u = kf[2 * m + 1];
            f32x4 s = {0.f, 0.f, 0.f, 0.f};
            s = __builtin_amdgcn_mfma_f32_16x16x32_f16(a0.h, qa0, s, 0, 0, 0);
            s = __builtin_amdgcn_mfma_f32_16x16x32_f16(a1.h, qa1, s, 0, 0, 0);

            kf[2 * m]     = *(const uint4*)(kp + (2 * m)     * 1024);
            kf[2 * m + 1] = *(const uint4*)(kp + (2 * m + 1) * 1024);

            if (last) {
                #pragma unroll
                for (int r2 = 0; r2 < 4; ++r2) {
                    const int kv_g = kt * 64 + 16 * m + 4 * l4 + r2;
                    if (kv_g > q_g) s[r2] = -1e30f;
                }
            }

            const float cmax = fmaxf(fmaxf(s[0], s[1]), fmaxf(s[2], s[3]));
            if (__any(cmax > m_run)) {            // slow path: never for N(0,1)
                float pm = cmax;
                pm = fmaxf(pm, __shfl_xor(pm, 16, 64));
                pm = fmaxf(pm, __shfl_xor(pm, 32, 64));
                const float m_new = fmaxf(m_run, pm);
                const float fac = __builtin_exp2f(m_run - m_new);
                m_run = m_new;
                lsum *= fac;
                float fr[4];
                #pragma unroll
                for (int r2 = 0; r2 < 4; ++r2) fr[r2] = __shfl(fac, 4 * l4 + r2, 64);
                #pragma unroll
                for (int c = 0; c < 4; ++c)
                    #pragma unroll
                    for (int r2 = 0; r2 < 4; ++r2) o[c][r2] *= fr[r2];
            }

            const float p0 = __builtin_exp2f(s[0] - m_run);
            const float p1 = __builtin_exp2f(s[1] - m_run);
            const float p2 = __builtin_exp2f(s[2] - m_run);
            const float p3 = __builtin_exp2f(s[3] - m_run);
            lsum += (p0 + p1) + (p2 + p3);
            union { f16x4 h; unsigned int u[2]; } pa;
            pa.u[0] = pk2(p0, p1);
            pa.u[1] = pk2(p2, p3);

            union { uint4 u; f16x4 h[2]; } w0, w1;
            w0.u = vf[2 * m]; w1.u = vf[2 * m + 1];
            o[0] = __builtin_amdgcn_mfma_f32_16x16x16f16(pa.h, w0.h[0], o[0], 0, 0, 0);
            o[1] = __builtin_amdgcn_mfma_f32_16x16x16f16(pa.h, w0.h[1], o[1], 0, 0, 0);
            o[2] = __builtin_amdgcn_mfma_f32_16x16x16f16(pa.h, w1.h[0], o[2], 0, 0, 0);
            o[3] = __builtin_amdgcn_mfma_f32_16x16x16f16(pa.h, w1.h[1], o[3], 0, 0, 0);

            vf[2 * m]     = *(const uint4*)(vp + (2 * m)     * 1024);
            vf[2 * m + 1] = *(const uint4*)(vp + (2 * m + 1) * 1024);
        }
    }

    // epilogue: finish l (sum over l4 groups), normalize, plain fp32 stores
    lsum += __shfl_xor(lsum, 16, 64);
    lsum += __shfl_xor(lsum, 32, 64);
    const float inv = 1.0f / lsum;            // q = l15 domain
    float ir[4];
    #pragma unroll
    for (int r2 = 0; r2 < 4; ++r2) ir[r2] = __shfl(inv, 4 * l4 + r2, 64);
    float* op = Out + base;
    #pragma unroll
    for (int c = 0; c < 4; ++c)
        #pragma unroll
        for (int r2 = 0; r2 < 4; ++r2)
            op[(size_t)(qrow0 + 4 * l4 + r2) * 512 + 16 * c + l15] = o[c][r2] * ir[r2];
}

extern "C" void kernel_launch(void* const* d_in, const int* in_sizes, int n_in,
                              void* d_out, int out_size, void* d_ws, size_t ws_size,
                              hipStream_t stream) {
    const float* Q = (const float*)d_in[0];
    const float* K = (const float*)d_in[1];
    const float* V = (const float*)d_in[2];
    float* O = (float*)d_out;
    char* ws = (char*)d_ws;   // 16 MB fragment-ordered tile images
    hipLaunchKernelGGL(prep_kernel, dim3(32 * NKV), dim3(256), 0, stream, K, V, ws);
    hipLaunchKernelGGL(fa_fwd_kernel, dim3(128 * 32), dim3(64), 0, stream, Q, ws, O);
}